// Round 9
// baseline (103.715 us; speedup 1.0000x reference)
//
#include <hip/hip_runtime.h>

#define T_LEN 512
#define LOG2E 1.4426950408889634f

typedef float f32x2 __attribute__((ext_vector_type(2)));

// v8: 2 batches per wave, R6's 64-lane layout per batch (lane l -> gate l&3,
// hidden k=l>>2, row = (l&3)*16+k), processed in ALTERNATING asm blocks so
// batch A's compute hides batch B's LDS round-trip and vice versa.
// DS queue (in-order retire): each block head waits lgkmcnt(6) = "my 6 DS ops
// from the previous step done; other batch's 6 still outstanding".
// Per-batch LDS region: [h 64][x 512][pad 16] = 592 floats. 8 regions/block.
__global__ __launch_bounds__(256, 1) void bilstm_head_kernel(
    const float* __restrict__ x,
    const float* __restrict__ W_ih_f, const float* __restrict__ W_hh_f,
    const float* __restrict__ b_ih_f, const float* __restrict__ b_hh_f,
    const float* __restrict__ W_ih_r, const float* __restrict__ W_hh_r,
    const float* __restrict__ b_ih_r, const float* __restrict__ b_hh_r,
    const float* __restrict__ W1, const float* __restrict__ b1,
    const float* __restrict__ W2, const float* __restrict__ b2,
    float* __restrict__ out)
{
    extern __shared__ float smem[];          // 8 regions * 592 floats

    const int tid  = threadIdx.x;
    const int wid  = tid >> 6;
    const int lane = tid & 63;
    const int bA   = blockIdx.x * 8 + wid * 2;
    const int bB   = bA + 1;

    const int gate = lane & 3;
    const int k    = lane >> 2;
    const int row  = gate * 16 + k;

    const bool  isg = (gate == 2);
    const float c1  = isg ? (-2.0f * LOG2E) : (-LOG2E);
    const float cm  = isg ? 2.0f : 1.0f;
    const float ca  = isg ? -1.0f : 0.0f;
    const float k2  = -2.0f * LOG2E;

    // prescaled weights (shared by both batches: same row per lane)
    const float wih_p  = W_ih_f[row] * c1;
    const float bias_p = (b_ih_f[row] + b_hh_f[row]) * c1;
    f32x2 wp[8];
#pragma unroll
    for (int n = 0; n < 8; ++n) {
        wp[n].x = W_hh_f[row * 16 + 2 * n]     * c1;
        wp[n].y = W_hh_f[row * 16 + 2 * n + 1] * c1;
    }

    const int rA = (wid * 2)     * 592;
    const int rB = (wid * 2 + 1) * 592;
    // stage both batches' x rows into LDS (coalesced)
#pragma unroll
    for (int i = 0; i < 8; ++i) {
        smem[rA + 64 + i * 64 + lane] = x[bA * T_LEN + i * 64 + lane];
        smem[rB + 64 + i * 64 + lane] = x[bB * T_LEN + i * 64 + lane];
    }

    const unsigned vBA = (unsigned)(rA * 4);
    const unsigned vBB = (unsigned)(rB * 4);
    const unsigned vWA = vBA + (unsigned)(row * 4);
    const unsigned vWB = vBB + (unsigned)(row * 4);
    unsigned vXA = vBA + 224;                // x base - 32 (pre-bump)
    unsigned vXB = vBB + 224;
    float cA = 0.0f, cB = 0.0f;

// one LSTM step for one batch. Head: wait my 6 DS (other batch's 6 remain).
// Tail: x-prefetch (mid, fills trans slot), h-write, 4 h-reads -- no wait.
#define STEP_A(XC, XN, XOFF) \
    "s_waitcnt lgkmcnt(6)\n\t" \
    "v_fma_f32 v20, " XC ", %[wih], %[bias]\n\t" \
    "v_mov_b32 v21, 0\n\t" \
    "v_pk_mul_f32 v[22:23], v[40:41], %[w89]\n\t" \
    "v_pk_fma_f32 v[20:21], v[32:33], %[w01], v[20:21]\n\t" \
    "v_pk_fma_f32 v[22:23], v[42:43], %[wAB], v[22:23]\n\t" \
    "v_pk_fma_f32 v[20:21], v[34:35], %[w23], v[20:21]\n\t" \
    "v_pk_fma_f32 v[22:23], v[44:45], %[wCD], v[22:23]\n\t" \
    "v_pk_fma_f32 v[20:21], v[36:37], %[w45], v[20:21]\n\t" \
    "v_pk_fma_f32 v[22:23], v[46:47], %[wEF], v[22:23]\n\t" \
    "v_pk_fma_f32 v[20:21], v[38:39], %[w67], v[20:21]\n\t" \
    "v_add_f32 v20, v20, v22\n\t" \
    "v_add_f32 v21, v21, v23\n\t" \
    "v_add_f32 v20, v20, v21\n\t" \
    "v_exp_f32 v24, v20\n\t" \
    "ds_read_b32 " XN ", %[vXA] offset:" XOFF "\n\t" \
    "s_nop 0\n\t" \
    "v_add_f32 v24, 1.0, v24\n\t" \
    "v_rcp_f32 v24, v24\n\t" \
    "s_nop 1\n\t" \
    "v_fma_f32 v25, v24, %[cm], %[ca]\n\t" \
    "s_nop 1\n\t" \
    "v_mov_b32_dpp v26, v25 quad_perm:[1,0,3,2] row_mask:0xf bank_mask:0xf\n\t" \
    "v_mov_b32_dpp v27, v25 quad_perm:[2,3,0,1] row_mask:0xf bank_mask:0xf\n\t" \
    "v_mov_b32_dpp v28, v25 quad_perm:[3,2,1,0] row_mask:0xf bank_mask:0xf\n\t" \
    "v_mul_f32 v24, v25, v27\n\t" \
    "v_fma_f32 %[cA], v26, %[cA], v24\n\t" \
    "v_mul_f32 v24, %[k2], %[cA]\n\t" \
    "v_exp_f32 v24, v24\n\t" \
    "s_nop 1\n\t" \
    "v_add_f32 v24, 1.0, v24\n\t" \
    "v_rcp_f32 v24, v24\n\t" \
    "s_nop 1\n\t" \
    "v_fma_f32 v24, v24, 2.0, -1.0\n\t" \
    "v_mul_f32 v29, v28, v24\n\t" \
    "ds_write_b32 %[vWA], v29\n\t" \
    "ds_read_b128 v[32:35], %[vBA] offset:0\n\t" \
    "ds_read_b128 v[36:39], %[vBA] offset:16\n\t" \
    "ds_read_b128 v[40:43], %[vBA] offset:32\n\t" \
    "ds_read_b128 v[44:47], %[vBA] offset:48\n\t"

#define STEP_B(XC, XN, XOFF) \
    "s_waitcnt lgkmcnt(6)\n\t" \
    "v_fma_f32 v20, " XC ", %[wih], %[bias]\n\t" \
    "v_mov_b32 v21, 0\n\t" \
    "v_pk_mul_f32 v[22:23], v[56:57], %[w89]\n\t" \
    "v_pk_fma_f32 v[20:21], v[48:49], %[w01], v[20:21]\n\t" \
    "v_pk_fma_f32 v[22:23], v[58:59], %[wAB], v[22:23]\n\t" \
    "v_pk_fma_f32 v[20:21], v[50:51], %[w23], v[20:21]\n\t" \
    "v_pk_fma_f32 v[22:23], v[60:61], %[wCD], v[22:23]\n\t" \
    "v_pk_fma_f32 v[20:21], v[52:53], %[w45], v[20:21]\n\t" \
    "v_pk_fma_f32 v[22:23], v[62:63], %[wEF], v[22:23]\n\t" \
    "v_pk_fma_f32 v[20:21], v[54:55], %[w67], v[20:21]\n\t" \
    "v_add_f32 v20, v20, v22\n\t" \
    "v_add_f32 v21, v21, v23\n\t" \
    "v_add_f32 v20, v20, v21\n\t" \
    "v_exp_f32 v24, v20\n\t" \
    "ds_read_b32 " XN ", %[vXB] offset:" XOFF "\n\t" \
    "s_nop 0\n\t" \
    "v_add_f32 v24, 1.0, v24\n\t" \
    "v_rcp_f32 v24, v24\n\t" \
    "s_nop 1\n\t" \
    "v_fma_f32 v25, v24, %[cm], %[ca]\n\t" \
    "s_nop 1\n\t" \
    "v_mov_b32_dpp v26, v25 quad_perm:[1,0,3,2] row_mask:0xf bank_mask:0xf\n\t" \
    "v_mov_b32_dpp v27, v25 quad_perm:[2,3,0,1] row_mask:0xf bank_mask:0xf\n\t" \
    "v_mov_b32_dpp v28, v25 quad_perm:[3,2,1,0] row_mask:0xf bank_mask:0xf\n\t" \
    "v_mul_f32 v24, v25, v27\n\t" \
    "v_fma_f32 %[cB], v26, %[cB], v24\n\t" \
    "v_mul_f32 v24, %[k2], %[cB]\n\t" \
    "v_exp_f32 v24, v24\n\t" \
    "s_nop 1\n\t" \
    "v_add_f32 v24, 1.0, v24\n\t" \
    "v_rcp_f32 v24, v24\n\t" \
    "s_nop 1\n\t" \
    "v_fma_f32 v24, v24, 2.0, -1.0\n\t" \
    "v_mul_f32 v29, v28, v24\n\t" \
    "ds_write_b32 %[vWB], v29\n\t" \
    "ds_read_b128 v[48:51], %[vBB] offset:0\n\t" \
    "ds_read_b128 v[52:55], %[vBB] offset:16\n\t" \
    "ds_read_b128 v[56:59], %[vBB] offset:32\n\t" \
    "ds_read_b128 v[60:63], %[vBB] offset:48\n\t"

    asm volatile(
        // preambles mimic a step tail per batch: x0 read, zero-h write, 4 reads
        "v_mov_b32 v29, 0\n\t"
        "ds_read_b32 v30, %[vBA] offset:256\n\t"
        "ds_write_b32 %[vWA], v29\n\t"
        "ds_read_b128 v[32:35], %[vBA] offset:0\n\t"
        "ds_read_b128 v[36:39], %[vBA] offset:16\n\t"
        "ds_read_b128 v[40:43], %[vBA] offset:32\n\t"
        "ds_read_b128 v[44:47], %[vBA] offset:48\n\t"
        "ds_read_b32 v18, %[vBB] offset:256\n\t"
        "ds_write_b32 %[vWB], v29\n\t"
        "ds_read_b128 v[48:51], %[vBB] offset:0\n\t"
        "ds_read_b128 v[52:55], %[vBB] offset:16\n\t"
        "ds_read_b128 v[56:59], %[vBB] offset:32\n\t"
        "ds_read_b128 v[60:63], %[vBB] offset:48\n\t"
        "s_mov_b32 s20, 0\n\t"
        "1:\n\t"
        "v_add_u32 %[vXA], 32, %[vXA]\n\t"
        "v_add_u32 %[vXB], 32, %[vXB]\n\t"
        STEP_A("v30", "v31", "4")  STEP_B("v18", "v19", "4")
        STEP_A("v31", "v30", "8")  STEP_B("v19", "v18", "8")
        STEP_A("v30", "v31", "12") STEP_B("v18", "v19", "12")
        STEP_A("v31", "v30", "16") STEP_B("v19", "v18", "16")
        STEP_A("v30", "v31", "20") STEP_B("v18", "v19", "20")
        STEP_A("v31", "v30", "24") STEP_B("v19", "v18", "24")
        STEP_A("v30", "v31", "28") STEP_B("v18", "v19", "28")
        STEP_A("v31", "v30", "32") STEP_B("v19", "v18", "32")
        "s_add_u32 s20, s20, 1\n\t"
        "s_cmp_lt_u32 s20, 64\n\t"
        "s_cbranch_scc1 1b\n\t"
        "s_waitcnt lgkmcnt(0)\n\t"
        : [cA]"+v"(cA), [cB]"+v"(cB), [vXA]"+v"(vXA), [vXB]"+v"(vXB)
        : [vBA]"v"(vBA), [vBB]"v"(vBB), [vWA]"v"(vWA), [vWB]"v"(vWB),
          [wih]"v"(wih_p), [bias]"v"(bias_p),
          [cm]"v"(cm), [ca]"v"(ca), [k2]"v"(k2),
          [w01]"v"(wp[0]), [w23]"v"(wp[1]), [w45]"v"(wp[2]), [w67]"v"(wp[3]),
          [w89]"v"(wp[4]), [wAB]"v"(wp[5]), [wCD]"v"(wp[6]), [wEF]"v"(wp[7])
        : "v18","v19","v20","v21","v22","v23","v24","v25","v26","v27","v28","v29",
          "v30","v31","v32","v33","v34","v35","v36","v37","v38","v39",
          "v40","v41","v42","v43","v44","v45","v46","v47",
          "v48","v49","v50","v51","v52","v53","v54","v55",
          "v56","v57","v58","v59","v60","v61","v62","v63",
          "s20","scc","memory");
#undef STEP_A
#undef STEP_B

    // ---- reverse direction: one step on x[:, T-1], zero state. lanes 0-15
    // handle batch A, 16-31 batch B; h_bwd stored in dead rows 16..31.
    if (lane < 32) {
        const int rb = (lane < 16) ? rA : rB;
        const int j  = lane & 15;
        const float xl = smem[rb + 64 + 511];
        const float zi = fmaf(xl, W_ih_r[j],      b_ih_r[j]      + b_hh_r[j]);
        const float zg = fmaf(xl, W_ih_r[32 + j], b_ih_r[32 + j] + b_hh_r[32 + j]);
        const float zo = fmaf(xl, W_ih_r[48 + j], b_ih_r[48 + j] + b_hh_r[48 + j]);
        const float si = __builtin_amdgcn_rcpf(1.0f + __builtin_amdgcn_exp2f(-zi * LOG2E));
        const float tg = fmaf(__builtin_amdgcn_rcpf(1.0f + __builtin_amdgcn_exp2f(-2.0f * zg * LOG2E)), 2.0f, -1.0f);
        const float so = __builtin_amdgcn_rcpf(1.0f + __builtin_amdgcn_exp2f(-zo * LOG2E));
        const float cr = si * tg;
        const float th = fmaf(__builtin_amdgcn_rcpf(1.0f + __builtin_amdgcn_exp2f(-2.0f * cr * LOG2E)), 2.0f, -1.0f);
        smem[rb + 16 + j] = so * th;
    }
    __syncthreads();

    // ---- MLP head: groups of 16 lanes; group0->A, group1->B (2,3 redundant)
    const int j  = lane & 15;
    const int g  = (lane >> 4) & 1;
    const int rb = g ? rB : rA;
    const int bo = g ? bB : bA;
    float hid = b1[j];
#pragma unroll
    for (int n = 0; n < 16; ++n) hid = fmaf(smem[rb + n],      W1[j * 32 + n],      hid);
#pragma unroll
    for (int n = 0; n < 16; ++n) hid = fmaf(smem[rb + 16 + n], W1[j * 32 + 16 + n], hid);
    hid = (hid > 0.0f) ? hid : (0.2f * hid);

    float v = hid * W2[j];
    v += __shfl_xor(v, 1);
    v += __shfl_xor(v, 2);
    v += __shfl_xor(v, 4);
    v += __shfl_xor(v, 8);
    if (j == 0 && lane < 32) out[bo] = v + b2[0];
}

extern "C" void kernel_launch(void* const* d_in, const int* in_sizes, int n_in,
                              void* d_out, int out_size, void* d_ws, size_t ws_size,
                              hipStream_t stream) {
    const float* x      = (const float*)d_in[0];
    const float* W_ih_f = (const float*)d_in[1];
    const float* W_hh_f = (const float*)d_in[2];
    const float* b_ih_f = (const float*)d_in[3];
    const float* b_hh_f = (const float*)d_in[4];
    const float* W_ih_r = (const float*)d_in[5];
    const float* W_hh_r = (const float*)d_in[6];
    const float* b_ih_r = (const float*)d_in[7];
    const float* b_hh_r = (const float*)d_in[8];
    const float* W1     = (const float*)d_in[9];
    const float* b1     = (const float*)d_in[10];
    const float* W2     = (const float*)d_in[11];
    const float* b2     = (const float*)d_in[12];
    float* out = (float*)d_out;

    const int B = in_sizes[0] / T_LEN;   // 2048
    dim3 grid(B / 8), block(256);
    size_t lds_bytes = 8 * 592 * sizeof(float);   // 18944 B/block
    hipLaunchKernelGGL(bilstm_head_kernel, grid, block, lds_bytes, stream,
                       x, W_ih_f, W_hh_f, b_ih_f, b_hh_f,
                       W_ih_r, W_hh_r, b_ih_r, b_hh_r,
                       W1, b1, W2, b2, out);
}

// Round 10
// 76.916 us; speedup vs baseline: 1.3484x; 1.3484x over previous
//
#include <hip/hip_runtime.h>

#define T_LEN 512
#define LOG2E 1.4426950408889634f

typedef float f32x2 __attribute__((ext_vector_type(2)));

__device__ __forceinline__ float rl(float v, int lane) {
    return __int_as_float(__builtin_amdgcn_readlane(__float_as_int(v), lane));
}
template<int CTRL>
__device__ __forceinline__ float qperm(float v) {
    return __int_as_float(__builtin_amdgcn_mov_dpp(__float_as_int(v), CTRL, 0xF, 0xF, true));
}

// v9 = v6 (proven 88.7 steady: 1 batch/wave, 2 waves/SIMD, single LDS round
// trip per step with staggered in-order lgkmcnt waits) plus:
//  (a) anti-phase stagger: co-resident partner blocks (b and b+256 on the
//      same CU under XCD round-robin dispatch) start ~128 cyc apart so one
//      wave's LDS stall overlaps the other's compute,
//  (b) DPP-operand fusion: g/o gate gathers folded into their consuming
//      muls (v_mul_f32_dpp), pk_add chain fold. DS pattern unchanged.
__global__ __launch_bounds__(256, 2) void bilstm_head_kernel(
    const float* __restrict__ x,
    const float* __restrict__ W_ih_f, const float* __restrict__ W_hh_f,
    const float* __restrict__ b_ih_f, const float* __restrict__ b_hh_f,
    const float* __restrict__ W_ih_r, const float* __restrict__ W_hh_r,
    const float* __restrict__ b_ih_r, const float* __restrict__ b_hh_r,
    const float* __restrict__ W1, const float* __restrict__ b1,
    const float* __restrict__ W2, const float* __restrict__ b2,
    float* __restrict__ out)
{
    extern __shared__ float smem[];          // 4 waves * 592 floats

    const int tid  = threadIdx.x;
    const int wid  = tid >> 6;
    const int lane = tid & 63;
    const int b    = blockIdx.x * 4 + wid;

    const int gate = lane & 3;
    const int k    = lane >> 2;
    const int row  = gate * 16 + k;

    const bool  isg = (gate == 2);
    const float c1  = isg ? (-2.0f * LOG2E) : (-LOG2E);
    const float cm  = isg ? 2.0f : 1.0f;
    const float ca  = isg ? -1.0f : 0.0f;
    const float k2  = -2.0f * LOG2E;

    // weights prescaled by c1 so the matvec result feeds v_exp directly
    const float wih_p  = W_ih_f[row] * c1;
    const float bias_p = (b_ih_f[row] + b_hh_f[row]) * c1;
    f32x2 wp[8];
#pragma unroll
    for (int n = 0; n < 8; ++n) {
        wp[n].x = W_hh_f[row * 16 + 2 * n]     * c1;
        wp[n].y = W_hh_f[row * 16 + 2 * n + 1] * c1;
    }

    const int wfl = wid * 592;               // wave base (floats)
    // stage this batch's x row into LDS (coalesced, wave-private region)
#pragma unroll
    for (int i = 0; i < 8; ++i)
        smem[wfl + 64 + i * 64 + lane] = x[b * T_LEN + i * 64 + lane];

    const unsigned hbase = (unsigned)(wfl * 4);      // LDS byte offsets
    unsigned xaddr = hbase + 224;                    // x base - 32 (pre-bump)
    const unsigned waddr = hbase + (unsigned)(row * 4);
    float c = 0.0f;

    // anti-phase stagger: the co-resident partner block (b vs b+256 on the
    // same CU) delays ~128 cyc so the two waves' LDS stalls interleave.
    if ((blockIdx.x >> 8) & 1) __builtin_amdgcn_s_sleep(2);

// one LSTM step. Outstanding DS at head (issue order): x(prev), write, r1..r4.
// In-order returns -> staggered partial waits; write+reads at tail, no wait.
#define LSTM_STEP(XC, XN, XOFF) \
    "s_waitcnt lgkmcnt(5)\n\t" \
    "v_fma_f32 v20, " XC ", %[wih], %[bias]\n\t" \
    "v_mov_b32 v21, 0\n\t" \
    "s_waitcnt lgkmcnt(3)\n\t" \
    "v_pk_fma_f32 v[20:21], v[32:33], %[w01], v[20:21]\n\t" \
    "v_pk_fma_f32 v[20:21], v[34:35], %[w23], v[20:21]\n\t" \
    "s_waitcnt lgkmcnt(2)\n\t" \
    "v_pk_fma_f32 v[20:21], v[36:37], %[w45], v[20:21]\n\t" \
    "v_pk_fma_f32 v[20:21], v[38:39], %[w67], v[20:21]\n\t" \
    "s_waitcnt lgkmcnt(1)\n\t" \
    "v_pk_mul_f32 v[24:25], v[40:41], %[w89]\n\t" \
    "v_pk_fma_f32 v[24:25], v[42:43], %[wAB], v[24:25]\n\t" \
    "s_waitcnt lgkmcnt(0)\n\t" \
    "v_pk_fma_f32 v[24:25], v[44:45], %[wCD], v[24:25]\n\t" \
    "v_pk_fma_f32 v[24:25], v[46:47], %[wEF], v[24:25]\n\t" \
    "v_pk_add_f32 v[20:21], v[20:21], v[24:25]\n\t" \
    "v_add_f32 v20, v20, v21\n\t" \
    "v_exp_f32 v22, v20\n\t" \
    "ds_read_b32 " XN ", %[vX] offset:" XOFF "\n\t" \
    "s_nop 0\n\t" \
    "v_add_f32 v22, 1.0, v22\n\t" \
    "v_rcp_f32 v22, v22\n\t" \
    "s_nop 1\n\t" \
    "v_fma_f32 v23, v22, %[cm], %[ca]\n\t" \
    "s_nop 1\n\t" \
    "v_mov_b32_dpp v26, v23 quad_perm:[1,0,3,2] row_mask:0xf bank_mask:0xf\n\t" \
    "v_mul_f32_dpp v22, v23, v23 quad_perm:[2,3,0,1] row_mask:0xf bank_mask:0xf\n\t" \
    "s_nop 0\n\t" \
    "v_fma_f32 %[c], v26, %[c], v22\n\t" \
    "v_mul_f32 v22, %[k2], %[c]\n\t" \
    "v_exp_f32 v22, v22\n\t" \
    "s_nop 1\n\t" \
    "v_add_f32 v22, 1.0, v22\n\t" \
    "v_rcp_f32 v22, v22\n\t" \
    "s_nop 1\n\t" \
    "v_fma_f32 v22, v22, 2.0, -1.0\n\t" \
    "v_mul_f32_dpp v29, v23, v22 quad_perm:[3,2,1,0] row_mask:0xf bank_mask:0xf\n\t" \
    "s_nop 0\n\t" \
    "ds_write_b32 %[vW], v29\n\t" \
    "ds_read_b128 v[32:35], %[vB] offset:0\n\t" \
    "ds_read_b128 v[36:39], %[vB] offset:16\n\t" \
    "ds_read_b128 v[40:43], %[vB] offset:32\n\t" \
    "ds_read_b128 v[44:47], %[vB] offset:48\n\t"

    asm volatile(
        // preamble: same 6-op DS pattern as a step tail ->
        // x0 read, zero-h write, 4 h reads (return zeros)
        "v_mov_b32 v29, 0\n\t"
        "ds_read_b32 v30, %[vB] offset:256\n\t"
        "ds_write_b32 %[vW], v29\n\t"
        "ds_read_b128 v[32:35], %[vB] offset:0\n\t"
        "ds_read_b128 v[36:39], %[vB] offset:16\n\t"
        "ds_read_b128 v[40:43], %[vB] offset:32\n\t"
        "ds_read_b128 v[44:47], %[vB] offset:48\n\t"
        "s_mov_b32 s20, 0\n\t"
        "1:\n\t"
        "v_add_u32 %[vX], 32, %[vX]\n\t"
        LSTM_STEP("v30", "v31", "4")
        LSTM_STEP("v31", "v30", "8")
        LSTM_STEP("v30", "v31", "12")
        LSTM_STEP("v31", "v30", "16")
        LSTM_STEP("v30", "v31", "20")
        LSTM_STEP("v31", "v30", "24")
        LSTM_STEP("v30", "v31", "28")
        LSTM_STEP("v31", "v30", "32")
        "s_add_u32 s20, s20, 1\n\t"
        "s_cmp_lt_u32 s20, 64\n\t"
        "s_cbranch_scc1 1b\n\t"
        "s_waitcnt lgkmcnt(0)\n\t"
        : [c]"+v"(c), [vX]"+v"(xaddr)
        : [vB]"v"(hbase), [vW]"v"(waddr),
          [wih]"v"(wih_p), [bias]"v"(bias_p),
          [cm]"v"(cm), [ca]"v"(ca), [k2]"v"(k2),
          [w01]"v"(wp[0]), [w23]"v"(wp[1]), [w45]"v"(wp[2]), [w67]"v"(wp[3]),
          [w89]"v"(wp[4]), [wAB]"v"(wp[5]), [wCD]"v"(wp[6]), [wEF]"v"(wp[7])
        : "v20","v21","v22","v23","v24","v25","v26","v27","v28","v29",
          "v30","v31","v32","v33","v34","v35","v36","v37","v38","v39",
          "v40","v41","v42","v43","v44","v45","v46","v47",
          "s20","scc","memory");
#undef LSTM_STEP

    // final forward hidden state sits in LDS gate-0 region
    float hs[16];
#pragma unroll
    for (int n = 0; n < 16; ++n) hs[n] = smem[wfl + n];

    // ---- reverse direction: single LSTM step on x[:, T-1] from zero state ----
    const float wihr  = W_ih_r[row];
    const float biasr = b_ih_r[row] + b_hh_r[row];
    const float xlast = smem[wfl + 64 + 511];

    const float zr   = fmaf(xlast, wihr, biasr);
    const float er   = __builtin_amdgcn_exp2f(zr * c1);
    const float rr_  = __builtin_amdgcn_rcpf(1.0f + er);
    const float actr = fmaf(rr_, cm, ca);
    const float gr   = qperm<0x4E>(actr);
    const float or_  = qperm<0x1B>(actr);
    const float cr   = actr * gr;                      // sig(i)*tanh(g), c0 = 0
    const float e2r  = __builtin_amdgcn_exp2f(cr * (-2.0f * LOG2E));
    const float thr_ = fmaf(__builtin_amdgcn_rcpf(1.0f + e2r), 2.0f, -1.0f);
    const float hbw  = or_ * thr_;

    float hr[16];
#pragma unroll
    for (int n = 0; n < 16; ++n) hr[n] = rl(hbw, 4 * n);

    // ---- MLP head: hid = LeakyReLU([h_fwd, h_bwd] @ W1.T + b1); out = hid @ W2.T + b2
    const int m = lane & 15;
    float hid = b1[m];
#pragma unroll
    for (int n = 0; n < 16; ++n) hid = fmaf(hs[n], W1[m * 32 + n], hid);
#pragma unroll
    for (int n = 0; n < 16; ++n) hid = fmaf(hr[n], W1[m * 32 + 16 + n], hid);
    hid = (hid > 0.0f) ? hid : (0.2f * hid);

    float v = hid * W2[m];
    v += __shfl_xor(v, 1);
    v += __shfl_xor(v, 2);
    v += __shfl_xor(v, 4);
    v += __shfl_xor(v, 8);
    if (lane == 0) out[b] = v + b2[0];
}

extern "C" void kernel_launch(void* const* d_in, const int* in_sizes, int n_in,
                              void* d_out, int out_size, void* d_ws, size_t ws_size,
                              hipStream_t stream) {
    const float* x      = (const float*)d_in[0];
    const float* W_ih_f = (const float*)d_in[1];
    const float* W_hh_f = (const float*)d_in[2];
    const float* b_ih_f = (const float*)d_in[3];
    const float* b_hh_f = (const float*)d_in[4];
    const float* W_ih_r = (const float*)d_in[5];
    const float* W_hh_r = (const float*)d_in[6];
    const float* b_ih_r = (const float*)d_in[7];
    const float* b_hh_r = (const float*)d_in[8];
    const float* W1     = (const float*)d_in[9];
    const float* b1     = (const float*)d_in[10];
    const float* W2     = (const float*)d_in[11];
    const float* b2     = (const float*)d_in[12];
    float* out = (float*)d_out;

    const int B = in_sizes[0] / T_LEN;   // 2048
    dim3 grid(B / 4), block(256);
    size_t lds_bytes = 4 * 592 * sizeof(float);   // 9472 B/block
    hipLaunchKernelGGL(bilstm_head_kernel, grid, block, lds_bytes, stream,
                       x, W_ih_f, W_hh_f, b_ih_f, b_hh_f,
                       W_ih_r, W_hh_r, b_ih_r, b_hh_r,
                       W1, b1, W2, b2, out);
}